// Round 6
// baseline (532.392 us; speedup 1.0000x reference)
//
#include <hip/hip_runtime.h>
#include <hip/hip_fp16.h>

constexpr int NN = 100000;   // nodes
constexpr int EE = 3200000;  // edges
constexpr int GG = 5000;     // graphs
constexpr float BNEPS = 1e-5f;

// CSR build via 128 dst-bins + LDS-staged scatter
constexpr int BINS = 128;
constexpr int NPB = (NN + BINS - 1) / BINS;      // 782 nodes per bin (fits 10 bits)
constexpr int BCHUNK = 8192;                     // edges per bin_edges chunk
constexpr int NBCH = (EE + BCHUNK - 1) / BCHUNK; // 391
constexpr int BINCAP2 = 96;                      // LDS staging per bin per chunk (mean 64, +4σ)
constexpr int BINREG = 27648;                    // pairs region stride (mean 25000, +16σ)
constexpr int LCAP = 26624;                      // LDS colA buffer entries (mean+10σ)
constexpr int CTR_STRIDE = 32;                   // pad counters to separate lines

typedef int int4v __attribute__((ext_vector_type(4)));
typedef _Float16 f16x8 __attribute__((ext_vector_type(8)));

// packed pair: (dstLocal << 17) | src   — src < 131072, dstLocal < 1024

// ---------------- pass 1: bin edges by dst bin (128 bins), packed uint32 entries ----------------

__global__ __launch_bounds__(1024) void bin_edges(const int* __restrict__ ei,
                                                  unsigned* __restrict__ pairs,
                                                  int* __restrict__ binCur) {
    __shared__ int bcnt[BINS];
    __shared__ int bbase[BINS];
    __shared__ unsigned buf[BINS][BINCAP2];
    const int t = threadIdx.x;
    const int lane = t & 63, wv = t >> 6;  // 16 waves
    for (int ch = blockIdx.x; ch < NBCH; ch += gridDim.x) {
        for (int k = t; k < BINS; k += 1024) bcnt[k] = 0;
        __syncthreads();
        const int qbase = ch * (BCHUNK / 4);
#pragma unroll
        for (int rep = 0; rep < 2; ++rep) {
            const int q = qbase + rep * 1024 + t;
            if (q < EE / 4) {
                int4v d = __builtin_nontemporal_load((const int4v*)(ei + EE) + q);
                int4v s = __builtin_nontemporal_load((const int4v*)ei + q);
                int dd[4] = {d.x, d.y, d.z, d.w};
                int ss[4] = {s.x, s.y, s.z, s.w};
#pragma unroll
                for (int k = 0; k < 4; ++k) {
                    int o = dd[k] / NPB;
                    unsigned pk = ((unsigned)(dd[k] - o * NPB) << 17) | (unsigned)ss[k];
                    int p = atomicAdd(&bcnt[o], 1);
                    if (p < BINCAP2) {
                        buf[o][p] = pk;
                    } else {  // rare overflow: direct write
                        int gp = atomicAdd(&binCur[o * CTR_STRIDE], 1);
                        pairs[(size_t)o * BINREG + gp] = pk;
                    }
                }
            }
        }
        __syncthreads();
        if (t < BINS) {
            int c = bcnt[t] < BINCAP2 ? bcnt[t] : BINCAP2;
            bbase[t] = atomicAdd(&binCur[t * CTR_STRIDE], c);
            bcnt[t] = c;
        }
        __syncthreads();
        // flush: wave wv handles bins wv, wv+16, ... (8 bins/wave, ~64 entries each)
        for (int o = wv; o < BINS; o += 16) {
            const int c = bcnt[o];
            const size_t base = (size_t)o * BINREG + bbase[o];
            for (int k = lane; k < c; k += 64) pairs[base + k] = buf[o][k];
        }
        __syncthreads();  // protect bcnt/buf reuse
    }
}

// ---------------- exclusive scan of bin totals -> global colA bases ----------------

__global__ void bin_base(const int* __restrict__ binCur, int* __restrict__ binBase) {
    __shared__ int s[BINS];
    const int t = threadIdx.x;  // 128 threads
    const int v = binCur[t * CTR_STRIDE];
    s[t] = v;
    __syncthreads();
    for (int off = 1; off < BINS; off <<= 1) {
        int add = (t >= off) ? s[t - off] : 0;
        __syncthreads();
        s[t] += add;
        __syncthreads();
    }
    binBase[t] = s[t] - v;  // exclusive
}

// ---------------- fused count + scan + scatter, one block per bin, all-LDS ----------------

__global__ __launch_bounds__(1024) void scatter_lds(const unsigned* __restrict__ pairs,
                                                    const int* __restrict__ binCur,
                                                    const int* __restrict__ binBase,
                                                    int* __restrict__ rowptr,
                                                    float* __restrict__ dinv,
                                                    int* __restrict__ colA) {
    __shared__ int scnt[NPB];     // count -> cursor
    __shared__ int sscan[1024];
    __shared__ int lbuf[LCAP];
    const int b = blockIdx.x;
    const int t = threadIdx.x;
    const int lo = b * NPB;
    const int hi = (lo + NPB < NN) ? lo + NPB : NN;
    const int nb = hi - lo;
    const int tot = binCur[b * CTR_STRIDE];
    const int base = binBase[b];
    const unsigned* p = pairs + (size_t)b * BINREG;
    for (int k = t; k < nb; k += 1024) scnt[k] = 0;
    __syncthreads();
    for (int q = t; q < tot; q += 1024) atomicAdd(&scnt[p[q] >> 17], 1);
    __syncthreads();
    const int myc = (t < nb) ? scnt[t] : 0;
    sscan[t] = myc;
    __syncthreads();
    for (int off = 1; off < 1024; off <<= 1) {
        int add = (t >= off) ? sscan[t - off] : 0;
        __syncthreads();
        sscan[t] += add;
        __syncthreads();
    }
    const int excl = sscan[t] - myc;
    if (t < nb) {
        rowptr[lo + t] = base + excl;
        dinv[lo + t] = rsqrtf((float)(myc + 1));  // +1 self-loop
        scnt[t] = excl;                           // becomes fill cursor
    }
    if (b == BINS - 1 && t == 0) rowptr[NN] = base + tot;
    __syncthreads();
    for (int q = t; q < tot; q += 1024) {
        unsigned e = p[q];
        int pos = atomicAdd(&scnt[e >> 17], 1);
        int src = (int)(e & 0x1FFFFu);
        if (pos < LCAP) lbuf[pos] = src;
        else colA[base + pos] = src;  // overflow beyond LDS cap (never expected)
    }
    __syncthreads();
    const int m = tot < LCAP ? tot : LCAP;
    for (int k = t; k < m; k += 1024) colA[base + k] = lbuf[k];
}

// ---------------- x pre-scale ----------------

__global__ void scale_x(const float* __restrict__ x, const float* __restrict__ dinv,
                        __half* __restrict__ xsc) {
    int idx = blockIdx.x * blockDim.x + threadIdx.x;
    if (idx < NN * 20) {
        int n = idx / 20;
        xsc[idx] = __float2half(x[idx] * dinv[n]);
    }
}

// ---------------- GEMM: fp16 in/out, BN-affine (from raw stats) + ReLU on input ----------------

template <int FIN, int FOUT, bool AFFINE, bool SCALED, bool STATS>
__global__ void gemm_k(const __half* __restrict__ hin,
                       const float* __restrict__ sumsIn, const float* __restrict__ ssqIn,
                       const float* __restrict__ g, const float* __restrict__ be,
                       const float* __restrict__ W, const float* __restrict__ dinv,
                       const float* __restrict__ bias,
                       __half* __restrict__ out,
                       float* __restrict__ sumsOut, float* __restrict__ ssqOut) {
    constexpr int NB = 256 / FOUT;  // nodes per group
    __shared__ float Wl[FIN * FOUT];
    __shared__ float rows[NB][FIN];
    __shared__ float aa[AFFINE ? FIN : 1], bb[AFFINE ? FIN : 1];
    const int t = threadIdx.x;
    if constexpr (AFFINE) {
        if (t < FIN) {
            float mu = sumsIn[t] / (float)NN;
            float var = ssqIn[t] / (float)NN - mu * mu;
            float a = g[t] * rsqrtf(var + BNEPS);
            aa[t] = a;
            bb[t] = be[t] - mu * a;
        }
    }
    for (int i = t; i < FIN * FOUT; i += 256) Wl[i] = W[i];
    const int c = t % FOUT, s = t / FOUT;
    const int ngrp = (NN + NB - 1) / NB;
    float sAcc = 0.f, qAcc = 0.f;
    for (int grp = blockIdx.x; grp < ngrp; grp += gridDim.x) {
        __syncthreads();
        for (int i = t; i < NB * FIN; i += 256) {
            int sn = i / FIN, k = i % FIN;
            int n2 = grp * NB + sn;
            float v = 0.f;
            if (n2 < NN) {
                v = __half2float(hin[(size_t)n2 * FIN + k]);
                if constexpr (AFFINE) {
                    v = aa[k] * v + bb[k];
                    v = v > 0.f ? v : 0.f;
                }
            }
            rows[sn][k] = v;
        }
        __syncthreads();
        int node = grp * NB + s;
        if (node < NN) {
            float acc = 0.f;
#pragma unroll
            for (int k = 0; k < FIN; ++k) acc += rows[s][k] * Wl[k * FOUT + c];
            if constexpr (SCALED) {
                out[(size_t)node * FOUT + c] = __float2half(acc * dinv[node]);
            } else {
                float val = acc + bias[c];
                out[(size_t)node * FOUT + c] = __float2half(val);
                if constexpr (STATS) { sAcc += val; qAcc += val * val; }
            }
        }
    }
    if constexpr (STATS) {
        __shared__ float ls[FOUT], lq[FOUT];
        __syncthreads();
        if (t < FOUT) { ls[t] = 0.f; lq[t] = 0.f; }
        __syncthreads();
        atomicAdd(&ls[c], sAcc);
        atomicAdd(&lq[c], qAcc);
        __syncthreads();
        if (t < FOUT) { atomicAdd(&sumsOut[t], ls[t]); atomicAdd(&ssqOut[t], lq[t]); }
    }
}

// ---------------- gather aggregation, half2-per-lane, fp16 out, optional fused BN stats ----------------

template <int H2, int OUTF, bool STATS>
__global__ void agg_half(const __half2* __restrict__ src, const int* __restrict__ rowptr,
                         const int* __restrict__ colA, const float* __restrict__ dinv,
                         const float* __restrict__ bias, __half* __restrict__ out,
                         float* __restrict__ sumsOut, float* __restrict__ ssqOut) {
    constexpr int SUB = 64 / H2;
    const int lane = threadIdx.x & 63;
    const int wid = (blockIdx.x * blockDim.x + threadIdx.x) >> 6;
    const int totalWaves = (gridDim.x * blockDim.x) >> 6;
    const int f = lane % H2;
    const int sub = lane / H2;
    const int stride = totalWaves * SUB;
    float bx = 0.f, by = 0.f;
    if (bias != nullptr) {
        bx = bias[2 * f];
        by = bias[2 * f + 1];
    }
    const int i0 = (sub < SUB) ? wid * SUB + sub : NN;  // idle tail lanes skip
    float sx = 0.f, qx = 0.f, sy = 0.f, qy = 0.f;
    for (int i = i0; i < NN; i += stride) {
        const int r0 = rowptr[i], r1 = rowptr[i + 1];
        float2 acc = __half22float2(src[(size_t)i * H2 + f]);
        float2 acc2 = {0.f, 0.f};
        int e = r0;
        for (; e + 3 < r1; e += 4) {
            int j0 = colA[e], j1 = colA[e + 1], j2 = colA[e + 2], j3 = colA[e + 3];
            float2 v0 = __half22float2(src[(size_t)j0 * H2 + f]);
            float2 v1 = __half22float2(src[(size_t)j1 * H2 + f]);
            float2 v2 = __half22float2(src[(size_t)j2 * H2 + f]);
            float2 v3 = __half22float2(src[(size_t)j3 * H2 + f]);
            acc.x += v0.x + v1.x;
            acc.y += v0.y + v1.y;
            acc2.x += v2.x + v3.x;
            acc2.y += v2.y + v3.y;
        }
        for (; e < r1; ++e) {
            float2 v = __half22float2(src[(size_t)colA[e] * H2 + f]);
            acc.x += v.x; acc.y += v.y;
        }
        acc.x += acc2.x; acc.y += acc2.y;
        const float d = dinv[i];
        float vx = d * acc.x + bx;
        float vy = d * acc.y + by;
        *(__half2*)(out + (size_t)i * OUTF + 2 * f) = __floats2half2_rn(vx, vy);
        if constexpr (STATS) { sx += vx; qx += vx * vx; sy += vy; qy += vy * vy; }
    }
    if constexpr (STATS) {
        __shared__ float ls[OUTF], lq[OUTF];
        const int t = threadIdx.x;
        if (t < OUTF) { ls[t] = 0.f; lq[t] = 0.f; }
        __syncthreads();
        atomicAdd(&ls[2 * f], sx);
        atomicAdd(&lq[2 * f], qx);
        atomicAdd(&ls[2 * f + 1], sy);
        atomicAdd(&lq[2 * f + 1], qy);
        __syncthreads();
        if (t < OUTF) { atomicAdd(&sumsOut[t], ls[t]); atomicAdd(&ssqOut[t], lq[t]); }
    }
}

// ---------------- GAT factorized precompute ----------------

__global__ void gat_mats(const float* __restrict__ Wg, const float* __restrict__ att_src,
                         const float* __restrict__ att_dst, const float* __restrict__ Wf,
                         const float* __restrict__ bg, float* __restrict__ Psrc,
                         float* __restrict__ Pdst, float* __restrict__ M,
                         float* __restrict__ bgW) {
    int t = threadIdx.x;  // 1024 threads, one block
    if (t < 128) {
        int k = t >> 3, h = t & 7;
        float s = 0.f, d = 0.f;
        for (int c = 0; c < 16; ++c) {
            float wv = Wg[k * 128 + h * 16 + c];
            s += wv * att_src[h * 16 + c];
            d += wv * att_dst[h * 16 + c];
        }
        Psrc[k * 8 + h] = s;
        Pdst[k * 8 + h] = d;
    } else if (t < 512) {
        int m = t - 128;
        if (m < 384) {
            int hk = m / 3, j = m - hk * 3;
            int H = hk >> 4, k = hk & 15;
            float s = 0.f;
            for (int c = 0; c < 16; ++c) s += Wg[k * 128 + H * 16 + c] * Wf[c * 3 + j];
            M[hk * 3 + j] = 0.125f * s;
        }
    } else if (t < 515) {
        int j = t - 512;
        float s = 0.f;
        for (int c = 0; c < 16; ++c) s += bg[c] * Wf[c * 3 + j];
        bgW[j] = s;
    }
}

// ---------------- gat_prez: z = relu(bn(h3)) as fp16 [NN,16] (32B rows) ----------------

__global__ void gat_prez(const __half* __restrict__ h3,
                         const float* __restrict__ sums3, const float* __restrict__ ssq3,
                         const float* __restrict__ g3, const float* __restrict__ be3,
                         __half* __restrict__ z) {
    __shared__ float aa[16], bb[16];
    int t = threadIdx.x;
    if (t < 16) {
        float mu = sums3[t] / (float)NN;
        float var = ssq3[t] / (float)NN - mu * mu;
        float a = g3[t] * rsqrtf(var + BNEPS);
        aa[t] = a;
        bb[t] = be3[t] - mu * a;
    }
    __syncthreads();
    int n = blockIdx.x * blockDim.x + t;
    if (n >= NN) return;
    const f16x8* hp = (const f16x8*)(h3 + (size_t)n * 16);
    f16x8 v0 = hp[0], v1 = hp[1];
    f16x8 o0, o1;
#pragma unroll
    for (int k = 0; k < 8; ++k) {
        float a0 = aa[k] * (float)v0[k] + bb[k];
        float a1 = aa[8 + k] * (float)v1[k] + bb[8 + k];
        o0[k] = (_Float16)(a0 > 0.f ? a0 : 0.f);
        o1[k] = (_Float16)(a1 > 0.f ? a1 : 0.f);
    }
    f16x8* zo = (f16x8*)(z + (size_t)n * 16);
    zo[0] = o0;
    zo[1] = o1;
}

// ---------------- gat_agg9: head-per-lane, f16x8 value-typed rows (no scratch) ----------------
// R5 lesson: (cast)&reg pointer reads defeat SROA -> c0/c1/n0/n1 lived in SCRATCH
// (WRITE_SIZE 66MB, identical under launch_bounds change). Fix: ext_vector f16x8 loads
// and (float)v[k] value conversions with unroll-constant k — fully register-resident.
// Lane ls = head; each lane derives asrc/adst on the fly (PsR/PdR register columns);
// fp32 acc; fused M-projection + pool atomics.

__device__ __forceinline__ float leaky02(float x) { return x > 0.f ? x : 0.2f * x; }

__global__ __launch_bounds__(256, 4) void gat_agg9(
        const f16x8* __restrict__ z8, const int* __restrict__ rowptr,
        const int* __restrict__ colA, const int* __restrict__ batch,
        const float* __restrict__ Psrc, const float* __restrict__ Pdst,
        const float* __restrict__ Mg, float* __restrict__ out) {
    __shared__ float Ml[384];
    for (int k = threadIdx.x; k < 384; k += 256) Ml[k] = Mg[k];
    __syncthreads();
    const int lane = threadIdx.x & 63;
    const int ls = lane & 7;     // head owned by this lane
    const int grp = lane >> 3;   // dst slot within wave
    const int wid = (blockIdx.x * blockDim.x + threadIdx.x) >> 6;
    const int totalWaves = (gridDim.x * blockDim.x) >> 6;
    const int stride = totalWaves * 8;
    float PsR[16], PdR[16];
#pragma unroll
    for (int k = 0; k < 16; ++k) {
        PsR[k] = Psrc[k * 8 + ls];
        PdR[k] = Pdst[k * 8 + ls];
    }
    for (int i = wid * 8 + grp; i < NN; i += stride) {
        const int r0 = rowptr[i], r1 = rowptr[i + 1];
        f16x8 c0 = z8[(size_t)i * 2], c1 = z8[(size_t)i * 2 + 1];  // self row
        int e = r0;
        int jn = (e < r1) ? __builtin_nontemporal_load(colA + e) : i;
        f16x8 n0 = z8[(size_t)jn * 2], n1 = z8[(size_t)jn * 2 + 1];
        float zf[16];
#pragma unroll
        for (int k = 0; k < 8; ++k) {
            zf[k] = (float)c0[k];
            zf[8 + k] = (float)c1[k];
        }
        float as = 0.f, ad = 0.f;
#pragma unroll
        for (int k = 0; k < 16; ++k) {
            as += zf[k] * PsR[k];
            ad += zf[k] * PdR[k];
        }
        const float adv = ad;
        float w = __expf(leaky02(as + adv));
        float ws = w;
        float acc[16];
#pragma unroll
        for (int k = 0; k < 16; ++k) acc[k] = w * zf[k];
        while (e < r1) {
            c0 = n0; c1 = n1;
            const int e2 = e + 1;
            jn = (e2 < r1) ? __builtin_nontemporal_load(colA + e2) : i;
            n0 = z8[(size_t)jn * 2]; n1 = z8[(size_t)jn * 2 + 1];
#pragma unroll
            for (int k = 0; k < 8; ++k) {
                zf[k] = (float)c0[k];
                zf[8 + k] = (float)c1[k];
            }
            float a2 = 0.f;
#pragma unroll
            for (int k = 0; k < 16; ++k) a2 += zf[k] * PsR[k];
            w = __expf(leaky02(a2 + adv));
            ws += w;
#pragma unroll
            for (int k = 0; k < 16; ++k) acc[k] += w * zf[k];
            e = e2;
        }
        // epilogue: normalize own head, project through M, 8-lane reduce, atomic to graph
        const float inv = 1.f / ws;
        float o0 = 0.f, o1 = 0.f, o2 = 0.f;
#pragma unroll
        for (int k = 0; k < 16; ++k) {
            const float v = acc[k] * inv;
            const float* m = &Ml[(ls * 16 + k) * 3];
            o0 += v * m[0];
            o1 += v * m[1];
            o2 += v * m[2];
        }
#pragma unroll
        for (int off = 1; off < 8; off <<= 1) {
            o0 += __shfl_xor(o0, off);
            o1 += __shfl_xor(o1, off);
            o2 += __shfl_xor(o2, off);
        }
        const int g = batch[i];
        if (ls < 3) {
            const float ov = (ls == 0) ? o0 : (ls == 1) ? o1 : o2;
            atomicAdd(&out[g * 3 + ls], ov);
        }
    }
}

// ---------------- graph bounds from sorted batch ----------------

__global__ void graph_bounds(const int* __restrict__ batch, int* __restrict__ gstart) {
    int n = blockIdx.x * blockDim.x + threadIdx.x;
    if (n < NN) {
        int bn = batch[n];
        int bp = (n == 0) ? -1 : batch[n - 1];
        for (int g = bp + 1; g <= bn; ++g) gstart[g] = n;
        if (n == NN - 1)
            for (int g = bn + 1; g <= GG; ++g) gstart[g] = NN;
    }
}

// ---------------- pool_init: out[g] = bf + cnt*bgW (gat_agg9 atomically accumulates rest) ----------------

__global__ void pool_init(const int* __restrict__ gstart, const float* __restrict__ bgW,
                          const float* __restrict__ bf, float* __restrict__ out) {
    int g = blockIdx.x * blockDim.x + threadIdx.x;
    if (g < GG) {
        float cnt = (float)(gstart[g + 1] - gstart[g]);
#pragma unroll
        for (int j = 0; j < 3; ++j) out[g * 3 + j] = cnt * bgW[j] + bf[j];
    }
}

// ---------------- launcher ----------------

extern "C" void kernel_launch(void* const* d_in, const int* in_sizes, int n_in,
                              void* d_out, int out_size, void* d_ws, size_t ws_size,
                              hipStream_t stream) {
    const float* x = (const float*)d_in[0];
    const int* ei = (const int*)d_in[1];
    const int* batch = (const int*)d_in[2];
    const float* W1 = (const float*)d_in[3];  const float* b1 = (const float*)d_in[4];
    const float* g1 = (const float*)d_in[5];  const float* be1 = (const float*)d_in[6];
    const float* W2 = (const float*)d_in[7];  const float* b2 = (const float*)d_in[8];
    const float* g2 = (const float*)d_in[9];  const float* be2 = (const float*)d_in[10];
    const float* W3 = (const float*)d_in[11]; const float* b3 = (const float*)d_in[12];
    const float* g3 = (const float*)d_in[13]; const float* be3 = (const float*)d_in[14];
    const float* Wg = (const float*)d_in[15];
    const float* att_src = (const float*)d_in[16];
    const float* att_dst = (const float*)d_in[17];
    const float* bg = (const float*)d_in[18];
    const float* Wf = (const float*)d_in[19];
    const float* bf = (const float*)d_in[20];
    float* out = (float*)d_out;

    char* w = (char*)d_ws;
    auto alloc = [&](size_t bytes) -> char* {
        char* p = w;
        w += (bytes + 255) & ~(size_t)255;
        return p;
    };
    // --- zeroed region (one memset) ---
    int* binCur = (int*)alloc((size_t)BINS * CTR_STRIDE * 4);
    float* sums1 = (float*)alloc(64 * 4); float* ssq1 = (float*)alloc(64 * 4);
    float* sums2 = (float*)alloc(32 * 4); float* ssq2 = (float*)alloc(32 * 4);
    float* sums3 = (float*)alloc(16 * 4); float* ssq3 = (float*)alloc(16 * 4);
    size_t zeroBytes = (size_t)(w - (char*)d_ws);
    // --- rest ---
    int* binBase = (int*)alloc((size_t)BINS * 4);
    float* Psrc = (float*)alloc(128 * 4);
    float* Pdst = (float*)alloc(128 * 4);
    float* Mm = (float*)alloc(384 * 4);
    float* bgW = (float*)alloc(3 * 4);
    int* gstart = (int*)alloc((size_t)(GG + 1) * 4);
    int* rowptr = (int*)alloc((size_t)(NN + 1) * 4);
    int* colA = (int*)alloc((size_t)EE * 4);
    float* dinv = (float*)alloc((size_t)NN * 4);
    char* A = alloc((size_t)NN * 64 * 4);  // 25.6 MB scratch block A
    char* B = alloc((size_t)NN * 64 * 4);  // 25.6 MB scratch block B

    // lifetime-based aliases (byte offsets are node-row strides)
    unsigned* pairs = (unsigned*)A;  // BINS*BINREG*4 = 14.2 MB, dead after scatter_lds
    __half* xsc  = (__half*)B;                         // [NN,20] fp16   4.0 MB @ B+0
    __half* aggx = (__half*)(B + (size_t)NN * 64);     // [NN,20] fp16   4.0 MB
    __half* h1   = (__half*)A;                         // [NN,64] fp16  12.8 MB @ A+0
    __half* hs2  = (__half*)B;                         // [NN,32] fp16   6.4 MB @ B+0 (xsc dead)
    __half* h2   = (__half*)(B + (size_t)NN * 64);     // [NN,32] fp16   6.4 MB (aggx dead)
    __half* hs3  = (__half*)A;                         // [NN,16] fp16   3.2 MB (h1 dead)
    __half* h3   = (__half*)(A + (size_t)NN * 32);     // [NN,16] fp16   3.2 MB
    __half* z    = (__half*)(A + (size_t)NN * 64);     // [NN,16] fp16   3.2 MB

    hipMemsetAsync(d_ws, 0, zeroBytes, stream);

    // CSR build: 128-bin pass (packed u32) + all-LDS count/scan/scatter
    bin_edges<<<256, 1024, 0, stream>>>(ei, pairs, binCur);
    bin_base<<<1, BINS, 0, stream>>>(binCur, binBase);
    scatter_lds<<<BINS, 1024, 0, stream>>>(pairs, binCur, binBase, rowptr, dinv, colA);
    gat_mats<<<1, 1024, 0, stream>>>(Wg, att_src, att_dst, Wf, bg, Psrc, Pdst, Mm, bgW);
    graph_bounds<<<(NN + 255) / 256, 256, 0, stream>>>(batch, gstart);
    pool_init<<<(GG + 255) / 256, 256, 0, stream>>>(gstart, bgW, bf, out);

    // layer 1: aggregate x first (20ch tight fp16), then GEMM 20->64 (+b1, fused BN stats)
    scale_x<<<(NN * 20 + 255) / 256, 256, 0, stream>>>(x, dinv, xsc);
    agg_half<10, 20, false><<<2048, 256, 0, stream>>>((const __half2*)xsc, rowptr, colA, dinv,
                                                      nullptr, aggx, nullptr, nullptr);
    gemm_k<20, 64, false, false, true><<<2048, 256, 0, stream>>>(
        aggx, nullptr, nullptr, nullptr, nullptr, W1, dinv, b1, h1, sums1, ssq1);

    // layer 2: 64 -> 32 (BN1 affine in-kernel; agg emits BN stats)
    gemm_k<64, 32, true, true, false><<<2048, 256, 0, stream>>>(
        h1, sums1, ssq1, g1, be1, W2, dinv, nullptr, hs2, nullptr, nullptr);
    agg_half<16, 32, true><<<2048, 256, 0, stream>>>((const __half2*)hs2, rowptr, colA, dinv,
                                                     b2, h2, sums2, ssq2);

    // layer 3: 32 -> 16
    gemm_k<32, 16, true, true, false><<<2048, 256, 0, stream>>>(
        h2, sums2, ssq2, g2, be2, W3, dinv, nullptr, hs3, nullptr, nullptr);
    agg_half<8, 16, true><<<2048, 256, 0, stream>>>((const __half2*)hs3, rowptr, colA, dinv,
                                                    b3, h3, sums3, ssq3);

    // GAT: z only (32B f16x8 rows); asrc/adst derived in-kernel; fused pool+classify
    gat_prez<<<(NN + 255) / 256, 256, 0, stream>>>(h3, sums3, ssq3, g3, be3, z);
    gat_agg9<<<3200, 256, 0, stream>>>((const f16x8*)z, rowptr, colA, batch, Psrc, Pdst,
                                       Mm, out);
}

// Round 7
// 500.039 us; speedup vs baseline: 1.0647x; 1.0647x over previous
//
#include <hip/hip_runtime.h>
#include <hip/hip_fp16.h>

constexpr int NN = 100000;   // nodes
constexpr int EE = 3200000;  // edges
constexpr int GG = 5000;     // graphs
constexpr float BNEPS = 1e-5f;

// CSR build via 128 dst-bins + LDS-staged scatter
constexpr int BINS = 128;
constexpr int NPB = (NN + BINS - 1) / BINS;      // 782 nodes per bin (fits 10 bits)
constexpr int BCHUNK = 8192;                     // edges per bin_edges chunk
constexpr int NBCH = (EE + BCHUNK - 1) / BCHUNK; // 391
constexpr int BINCAP2 = 96;                      // LDS staging per bin per chunk (mean 64, +4σ)
constexpr int BINREG = 27648;                    // pairs region stride (mean 25000, +16σ)
constexpr int LCAP = 26624;                      // LDS colA buffer entries (mean+10σ)
constexpr int CTR_STRIDE = 32;                   // pad counters to separate lines

typedef int int4v __attribute__((ext_vector_type(4)));
typedef _Float16 f16x8 __attribute__((ext_vector_type(8)));

// packed pair: (dstLocal << 17) | src   — src < 131072, dstLocal < 1024

// ---------------- pass 1: bin edges by dst bin (128 bins), packed uint32 entries ----------------

__global__ __launch_bounds__(1024) void bin_edges(const int* __restrict__ ei,
                                                  unsigned* __restrict__ pairs,
                                                  int* __restrict__ binCur) {
    __shared__ int bcnt[BINS];
    __shared__ int bbase[BINS];
    __shared__ unsigned buf[BINS][BINCAP2];
    const int t = threadIdx.x;
    const int lane = t & 63, wv = t >> 6;  // 16 waves
    for (int ch = blockIdx.x; ch < NBCH; ch += gridDim.x) {
        for (int k = t; k < BINS; k += 1024) bcnt[k] = 0;
        __syncthreads();
        const int qbase = ch * (BCHUNK / 4);
#pragma unroll
        for (int rep = 0; rep < 2; ++rep) {
            const int q = qbase + rep * 1024 + t;
            if (q < EE / 4) {
                int4v d = __builtin_nontemporal_load((const int4v*)(ei + EE) + q);
                int4v s = __builtin_nontemporal_load((const int4v*)ei + q);
                int dd[4] = {d.x, d.y, d.z, d.w};
                int ss[4] = {s.x, s.y, s.z, s.w};
#pragma unroll
                for (int k = 0; k < 4; ++k) {
                    int o = dd[k] / NPB;
                    unsigned pk = ((unsigned)(dd[k] - o * NPB) << 17) | (unsigned)ss[k];
                    int p = atomicAdd(&bcnt[o], 1);
                    if (p < BINCAP2) {
                        buf[o][p] = pk;
                    } else {  // rare overflow: direct write
                        int gp = atomicAdd(&binCur[o * CTR_STRIDE], 1);
                        pairs[(size_t)o * BINREG + gp] = pk;
                    }
                }
            }
        }
        __syncthreads();
        if (t < BINS) {
            int c = bcnt[t] < BINCAP2 ? bcnt[t] : BINCAP2;
            bbase[t] = atomicAdd(&binCur[t * CTR_STRIDE], c);
            bcnt[t] = c;
        }
        __syncthreads();
        // flush: wave wv handles bins wv, wv+16, ... (8 bins/wave, ~64 entries each)
        for (int o = wv; o < BINS; o += 16) {
            const int c = bcnt[o];
            const size_t base = (size_t)o * BINREG + bbase[o];
            for (int k = lane; k < c; k += 64) pairs[base + k] = buf[o][k];
        }
        __syncthreads();  // protect bcnt/buf reuse
    }
}

// ---------------- exclusive scan of bin totals -> global colA bases ----------------

__global__ void bin_base(const int* __restrict__ binCur, int* __restrict__ binBase) {
    __shared__ int s[BINS];
    const int t = threadIdx.x;  // 128 threads
    const int v = binCur[t * CTR_STRIDE];
    s[t] = v;
    __syncthreads();
    for (int off = 1; off < BINS; off <<= 1) {
        int add = (t >= off) ? s[t - off] : 0;
        __syncthreads();
        s[t] += add;
        __syncthreads();
    }
    binBase[t] = s[t] - v;  // exclusive
}

// ---------------- fused count + scan + scatter, one block per bin, all-LDS ----------------

__global__ __launch_bounds__(1024) void scatter_lds(const unsigned* __restrict__ pairs,
                                                    const int* __restrict__ binCur,
                                                    const int* __restrict__ binBase,
                                                    int* __restrict__ rowptr,
                                                    float* __restrict__ dinv,
                                                    int* __restrict__ colA) {
    __shared__ int scnt[NPB];     // count -> cursor
    __shared__ int sscan[1024];
    __shared__ int lbuf[LCAP];
    const int b = blockIdx.x;
    const int t = threadIdx.x;
    const int lo = b * NPB;
    const int hi = (lo + NPB < NN) ? lo + NPB : NN;
    const int nb = hi - lo;
    const int tot = binCur[b * CTR_STRIDE];
    const int base = binBase[b];
    const unsigned* p = pairs + (size_t)b * BINREG;
    for (int k = t; k < nb; k += 1024) scnt[k] = 0;
    __syncthreads();
    for (int q = t; q < tot; q += 1024) atomicAdd(&scnt[p[q] >> 17], 1);
    __syncthreads();
    const int myc = (t < nb) ? scnt[t] : 0;
    sscan[t] = myc;
    __syncthreads();
    for (int off = 1; off < 1024; off <<= 1) {
        int add = (t >= off) ? sscan[t - off] : 0;
        __syncthreads();
        sscan[t] += add;
        __syncthreads();
    }
    const int excl = sscan[t] - myc;
    if (t < nb) {
        rowptr[lo + t] = base + excl;
        dinv[lo + t] = rsqrtf((float)(myc + 1));  // +1 self-loop
        scnt[t] = excl;                           // becomes fill cursor
    }
    if (b == BINS - 1 && t == 0) rowptr[NN] = base + tot;
    __syncthreads();
    for (int q = t; q < tot; q += 1024) {
        unsigned e = p[q];
        int pos = atomicAdd(&scnt[e >> 17], 1);
        int src = (int)(e & 0x1FFFFu);
        if (pos < LCAP) lbuf[pos] = src;
        else colA[base + pos] = src;  // overflow beyond LDS cap (never expected)
    }
    __syncthreads();
    const int m = tot < LCAP ? tot : LCAP;
    for (int k = t; k < m; k += 1024) colA[base + k] = lbuf[k];
}

// ---------------- x pre-scale ----------------

__global__ void scale_x(const float* __restrict__ x, const float* __restrict__ dinv,
                        __half* __restrict__ xsc) {
    int idx = blockIdx.x * blockDim.x + threadIdx.x;
    if (idx < NN * 20) {
        int n = idx / 20;
        xsc[idx] = __float2half(x[idx] * dinv[n]);
    }
}

// ---------------- GEMM: fp16 in/out, BN-affine (from raw stats) + ReLU on input ----------------

template <int FIN, int FOUT, bool AFFINE, bool SCALED, bool STATS>
__global__ void gemm_k(const __half* __restrict__ hin,
                       const float* __restrict__ sumsIn, const float* __restrict__ ssqIn,
                       const float* __restrict__ g, const float* __restrict__ be,
                       const float* __restrict__ W, const float* __restrict__ dinv,
                       const float* __restrict__ bias,
                       __half* __restrict__ out,
                       float* __restrict__ sumsOut, float* __restrict__ ssqOut) {
    constexpr int NB = 256 / FOUT;  // nodes per group
    __shared__ float Wl[FIN * FOUT];
    __shared__ float rows[NB][FIN];
    __shared__ float aa[AFFINE ? FIN : 1], bb[AFFINE ? FIN : 1];
    const int t = threadIdx.x;
    if constexpr (AFFINE) {
        if (t < FIN) {
            float mu = sumsIn[t] / (float)NN;
            float var = ssqIn[t] / (float)NN - mu * mu;
            float a = g[t] * rsqrtf(var + BNEPS);
            aa[t] = a;
            bb[t] = be[t] - mu * a;
        }
    }
    for (int i = t; i < FIN * FOUT; i += 256) Wl[i] = W[i];
    const int c = t % FOUT, s = t / FOUT;
    const int ngrp = (NN + NB - 1) / NB;
    float sAcc = 0.f, qAcc = 0.f;
    for (int grp = blockIdx.x; grp < ngrp; grp += gridDim.x) {
        __syncthreads();
        for (int i = t; i < NB * FIN; i += 256) {
            int sn = i / FIN, k = i % FIN;
            int n2 = grp * NB + sn;
            float v = 0.f;
            if (n2 < NN) {
                v = __half2float(hin[(size_t)n2 * FIN + k]);
                if constexpr (AFFINE) {
                    v = aa[k] * v + bb[k];
                    v = v > 0.f ? v : 0.f;
                }
            }
            rows[sn][k] = v;
        }
        __syncthreads();
        int node = grp * NB + s;
        if (node < NN) {
            float acc = 0.f;
#pragma unroll
            for (int k = 0; k < FIN; ++k) acc += rows[s][k] * Wl[k * FOUT + c];
            if constexpr (SCALED) {
                out[(size_t)node * FOUT + c] = __float2half(acc * dinv[node]);
            } else {
                float val = acc + bias[c];
                out[(size_t)node * FOUT + c] = __float2half(val);
                if constexpr (STATS) { sAcc += val; qAcc += val * val; }
            }
        }
    }
    if constexpr (STATS) {
        __shared__ float ls[FOUT], lq[FOUT];
        __syncthreads();
        if (t < FOUT) { ls[t] = 0.f; lq[t] = 0.f; }
        __syncthreads();
        atomicAdd(&ls[c], sAcc);
        atomicAdd(&lq[c], qAcc);
        __syncthreads();
        if (t < FOUT) { atomicAdd(&sumsOut[t], ls[t]); atomicAdd(&ssqOut[t], lq[t]); }
    }
}

// ---------------- gather aggregation, half2-per-lane, fp16 out, optional fused BN stats ----------------
// colA is a read-once stream: NT loads keep it from evicting the gather hot set in L2.
// (NT on LOADS of dead-after-read data only — R4 showed NT stores on producer arrays
// poison producer->consumer L2 reuse.)

template <int H2, int OUTF, bool STATS>
__global__ void agg_half(const __half2* __restrict__ src, const int* __restrict__ rowptr,
                         const int* __restrict__ colA, const float* __restrict__ dinv,
                         const float* __restrict__ bias, __half* __restrict__ out,
                         float* __restrict__ sumsOut, float* __restrict__ ssqOut) {
    constexpr int SUB = 64 / H2;
    const int lane = threadIdx.x & 63;
    const int wid = (blockIdx.x * blockDim.x + threadIdx.x) >> 6;
    const int totalWaves = (gridDim.x * blockDim.x) >> 6;
    const int f = lane % H2;
    const int sub = lane / H2;
    const int stride = totalWaves * SUB;
    float bx = 0.f, by = 0.f;
    if (bias != nullptr) {
        bx = bias[2 * f];
        by = bias[2 * f + 1];
    }
    const int i0 = (sub < SUB) ? wid * SUB + sub : NN;  // idle tail lanes skip
    float sx = 0.f, qx = 0.f, sy = 0.f, qy = 0.f;
    for (int i = i0; i < NN; i += stride) {
        const int r0 = rowptr[i], r1 = rowptr[i + 1];
        float2 acc = __half22float2(src[(size_t)i * H2 + f]);
        float2 acc2 = {0.f, 0.f};
        int e = r0;
        for (; e + 3 < r1; e += 4) {
            int j0 = __builtin_nontemporal_load(colA + e);
            int j1 = __builtin_nontemporal_load(colA + e + 1);
            int j2 = __builtin_nontemporal_load(colA + e + 2);
            int j3 = __builtin_nontemporal_load(colA + e + 3);
            float2 v0 = __half22float2(src[(size_t)j0 * H2 + f]);
            float2 v1 = __half22float2(src[(size_t)j1 * H2 + f]);
            float2 v2 = __half22float2(src[(size_t)j2 * H2 + f]);
            float2 v3 = __half22float2(src[(size_t)j3 * H2 + f]);
            acc.x += v0.x + v1.x;
            acc.y += v0.y + v1.y;
            acc2.x += v2.x + v3.x;
            acc2.y += v2.y + v3.y;
        }
        for (; e < r1; ++e) {
            int j = __builtin_nontemporal_load(colA + e);
            float2 v = __half22float2(src[(size_t)j * H2 + f]);
            acc.x += v.x; acc.y += v.y;
        }
        acc.x += acc2.x; acc.y += acc2.y;
        const float d = dinv[i];
        float vx = d * acc.x + bx;
        float vy = d * acc.y + by;
        *(__half2*)(out + (size_t)i * OUTF + 2 * f) = __floats2half2_rn(vx, vy);
        if constexpr (STATS) { sx += vx; qx += vx * vx; sy += vy; qy += vy * vy; }
    }
    if constexpr (STATS) {
        __shared__ float ls[OUTF], lq[OUTF];
        const int t = threadIdx.x;
        if (t < OUTF) { ls[t] = 0.f; lq[t] = 0.f; }
        __syncthreads();
        atomicAdd(&ls[2 * f], sx);
        atomicAdd(&lq[2 * f], qx);
        atomicAdd(&ls[2 * f + 1], sy);
        atomicAdd(&lq[2 * f + 1], qy);
        __syncthreads();
        if (t < OUTF) { atomicAdd(&sumsOut[t], ls[t]); atomicAdd(&ssqOut[t], lq[t]); }
    }
}

// ---------------- GAT factorized precompute ----------------

__global__ void gat_mats(const float* __restrict__ Wg, const float* __restrict__ att_src,
                         const float* __restrict__ att_dst, const float* __restrict__ Wf,
                         const float* __restrict__ bg, float* __restrict__ Psrc,
                         float* __restrict__ Pdst, float* __restrict__ M,
                         float* __restrict__ bgW) {
    int t = threadIdx.x;  // 1024 threads, one block
    if (t < 128) {
        int k = t >> 3, h = t & 7;
        float s = 0.f, d = 0.f;
        for (int c = 0; c < 16; ++c) {
            float wv = Wg[k * 128 + h * 16 + c];
            s += wv * att_src[h * 16 + c];
            d += wv * att_dst[h * 16 + c];
        }
        Psrc[k * 8 + h] = s;
        Pdst[k * 8 + h] = d;
    } else if (t < 512) {
        int m = t - 128;
        if (m < 384) {
            int hk = m / 3, j = m - hk * 3;
            int H = hk >> 4, k = hk & 15;
            float s = 0.f;
            for (int c = 0; c < 16; ++c) s += Wg[k * 128 + H * 16 + c] * Wf[c * 3 + j];
            M[hk * 3 + j] = 0.125f * s;
        }
    } else if (t < 515) {
        int j = t - 512;
        float s = 0.f;
        for (int c = 0; c < 16; ++c) s += bg[c] * Wf[c * 3 + j];
        bgW[j] = s;
    }
}

// ---------------- gat_pre2: interleaved zas row [z fp16 32B | asrc fp32 32B] + adst ----------------
// (Verified structure from R2/R3: one 64B line per edge gather in gat_agg7.)

__global__ void gat_pre2(const __half* __restrict__ h3,
                         const float* __restrict__ sums3, const float* __restrict__ ssq3,
                         const float* __restrict__ g3, const float* __restrict__ be3,
                         const float* __restrict__ Psrc, const float* __restrict__ Pdst,
                         float4* __restrict__ zas, float* __restrict__ adst) {
    __shared__ float Ps[128], Pd[128], aa[16], bb[16];
    int t = threadIdx.x;
    if (t < 128) { Ps[t] = Psrc[t]; Pd[t] = Pdst[t]; }
    if (t < 16) {
        float mu = sums3[t] / (float)NN;
        float var = ssq3[t] / (float)NN - mu * mu;
        float a = g3[t] * rsqrtf(var + BNEPS);
        aa[t] = a;
        bb[t] = be3[t] - mu * a;
    }
    __syncthreads();
    int n = blockIdx.x * blockDim.x + t;
    if (n >= NN) return;
    const f16x8* hp = (const f16x8*)(h3 + (size_t)n * 16);
    f16x8 v0 = hp[0], v1 = hp[1];
    float zv[16];
#pragma unroll
    for (int k = 0; k < 8; ++k) {
        float a0 = aa[k] * (float)v0[k] + bb[k];
        float a1 = aa[8 + k] * (float)v1[k] + bb[8 + k];
        zv[k] = a0 > 0.f ? a0 : 0.f;
        zv[8 + k] = a1 > 0.f ? a1 : 0.f;
    }
    f16x8 zh0, zh1;
#pragma unroll
    for (int k = 0; k < 8; ++k) {
        zh0[k] = (_Float16)zv[k];
        zh1[k] = (_Float16)zv[8 + k];
    }
    float as[8], ad[8];
#pragma unroll
    for (int h = 0; h < 8; ++h) { as[h] = 0.f; ad[h] = 0.f; }
#pragma unroll
    for (int k = 0; k < 16; ++k) {
        float zk = zv[k];
#pragma unroll
        for (int h = 0; h < 8; ++h) {
            as[h] += zk * Ps[k * 8 + h];
            ad[h] += zk * Pd[k * 8 + h];
        }
    }
    f16x8* zrow16 = (f16x8*)(zas + (size_t)n * 4);  // 64B row: [0..31]=z fp16, [32..63]=asrc fp32
    zrow16[0] = zh0;
    zrow16[1] = zh1;
    float4* zrow = zas + (size_t)n * 4;
    zrow[2] = make_float4(as[0], as[1], as[2], as[3]);
    zrow[3] = make_float4(as[4], as[5], as[6], as[7]);
    float4* d4 = (float4*)(adst + (size_t)n * 8);
    d4[0] = make_float4(ad[0], ad[1], ad[2], ad[3]);
    d4[1] = make_float4(ad[4], ad[5], ad[6], ad[7]);
}

// ---------------- gat_agg7: group-per-dst, 2-wide pipelined gathers, fused M-projection ----------------
// Verified @67.7µs, VGPR 60, WRITE 3.7MB (R2/R3). Head-per-lane variants (agg8/9) hit a
// structural SROA failure (64-float state across irregular loop -> scratch, 66-72MB writes)
// twice; reverted for good.

__device__ __forceinline__ float leaky02(float x) { return x > 0.f ? x : 0.2f * x; }

__global__ void gat_agg7(const float4* __restrict__ zas, const float* __restrict__ adst,
                         const int* __restrict__ rowptr, const int* __restrict__ colA,
                         const int* __restrict__ batch, const float* __restrict__ Mg,
                         float* __restrict__ out) {
    __shared__ float Ml[384];
    for (int k = threadIdx.x; k < 384; k += 256) Ml[k] = Mg[k];
    __syncthreads();
    const int lane = threadIdx.x & 63;
    const int ls = lane & 7;        // lane within group: also the head this lane exp's
    const int q = ls & 3;           // channel quad
    const int hh = ls >> 2;         // head half
    const int grp = lane >> 3;      // 8 dst-groups per wave
    const int gb = lane & 56;       // group base lane for shuffles
    const int wid = (blockIdx.x * blockDim.x + threadIdx.x) >> 6;
    const int totalWaves = (gridDim.x * blockDim.x) >> 6;
    const int stride = totalWaves * 8;
    const char* zb = (const char*)zas;
    for (int i = wid * 8 + grp; i < NN; i += stride) {
        const int r0 = rowptr[i], r1 = rowptr[i + 1];
        const float adv = __builtin_nontemporal_load(adst + (size_t)i * 8 + ls);
        float acc[4][4];
        float wsum[4];
#pragma unroll
        for (int h = 0; h < 4; ++h) {
            wsum[h] = 0.f;
#pragma unroll
            for (int k = 0; k < 4; ++k) acc[h][k] = 0.f;
        }
        auto compute = [&](float av, float2 zr, bool val) {
            const __half2* zp = (const __half2*)&zr;
            const float2 f0 = __half22float2(zp[0]), f1 = __half22float2(zp[1]);
            const float zf[4] = {f0.x, f0.y, f1.x, f1.y};
            const float w = val ? __expf(leaky02(av + adv)) : 0.f;
            float wq[4];
#pragma unroll
            for (int h = 0; h < 4; ++h) wq[h] = __shfl(w, gb + hh * 4 + h);
#pragma unroll
            for (int h = 0; h < 4; ++h) {
                wsum[h] += wq[h];
#pragma unroll
                for (int k = 0; k < 4; ++k) acc[h][k] += wq[h] * zf[k];
            }
        };
        // prologue: pair 0 = (self, first edge)
        int e = r0;
        int jA = i, jB = i;
        bool vB = false;
        if (e < r1) { jB = colA[e]; ++e; vB = true; }
        const char* rowA = zb + (size_t)jA * 64;
        const char* rowB = zb + (size_t)jB * 64;
        float avA = *(const float*)(rowA + 32 + ls * 4);
        float2 zA = *(const float2*)(rowA + q * 8);
        float avB = *(const float*)(rowB + 32 + ls * 4);
        float2 zB = *(const float2*)(rowB + q * 8);
        while (true) {
            // prefetch next pair (indices then rows) BEFORE computing current pair
            int jA2 = i, jB2 = i;
            bool vA2 = false, vB2 = false;
            if (e < r1) { jA2 = colA[e]; ++e; vA2 = true; }
            if (e < r1) { jB2 = colA[e]; ++e; vB2 = true; }
            const char* rA2 = zb + (size_t)jA2 * 64;
            const char* rB2 = zb + (size_t)jB2 * 64;
            float avA2 = *(const float*)(rA2 + 32 + ls * 4);
            float2 zA2 = *(const float2*)(rA2 + q * 8);
            float avB2 = *(const float*)(rB2 + 32 + ls * 4);
            float2 zB2 = *(const float2*)(rB2 + q * 8);
            compute(avA, zA, true);   // A slot of in-flight pair is always valid
            compute(avB, zB, vB);
            if (!vA2) break;
            avA = avA2; zA = zA2; avB = avB2; zB = zB2; vB = vB2;
        }
        // epilogue: normalize, project through M, group-reduce, atomic into out[graph]
        float o0 = 0.f, o1 = 0.f, o2 = 0.f;
#pragma unroll
        for (int h = 0; h < 4; ++h) {
            const float inv = 1.f / wsum[h];
            const int hk0 = (hh * 4 + h) * 16 + q * 4;
#pragma unroll
            for (int k = 0; k < 4; ++k) {
                const float v = acc[h][k] * inv;
                const float* m = &Ml[(hk0 + k) * 3];
                o0 += v * m[0];
                o1 += v * m[1];
                o2 += v * m[2];
            }
        }
#pragma unroll
        for (int off = 1; off < 8; off <<= 1) {
            o0 += __shfl_xor(o0, off);
            o1 += __shfl_xor(o1, off);
            o2 += __shfl_xor(o2, off);
        }
        const int g = batch[i];
        if (ls < 3) {
            const float ov = (ls == 0) ? o0 : (ls == 1) ? o1 : o2;
            atomicAdd(&out[g * 3 + ls], ov);
        }
    }
}

// ---------------- graph bounds from sorted batch ----------------

__global__ void graph_bounds(const int* __restrict__ batch, int* __restrict__ gstart) {
    int n = blockIdx.x * blockDim.x + threadIdx.x;
    if (n < NN) {
        int bn = batch[n];
        int bp = (n == 0) ? -1 : batch[n - 1];
        for (int g = bp + 1; g <= bn; ++g) gstart[g] = n;
        if (n == NN - 1)
            for (int g = bn + 1; g <= GG; ++g) gstart[g] = NN;
    }
}

// ---------------- pool_init: out[g] = bf + cnt*bgW (gat_agg7 atomically accumulates rest) ----------------

__global__ void pool_init(const int* __restrict__ gstart, const float* __restrict__ bgW,
                          const float* __restrict__ bf, float* __restrict__ out) {
    int g = blockIdx.x * blockDim.x + threadIdx.x;
    if (g < GG) {
        float cnt = (float)(gstart[g + 1] - gstart[g]);
#pragma unroll
        for (int j = 0; j < 3; ++j) out[g * 3 + j] = cnt * bgW[j] + bf[j];
    }
}

// ---------------- launcher ----------------

extern "C" void kernel_launch(void* const* d_in, const int* in_sizes, int n_in,
                              void* d_out, int out_size, void* d_ws, size_t ws_size,
                              hipStream_t stream) {
    const float* x = (const float*)d_in[0];
    const int* ei = (const int*)d_in[1];
    const int* batch = (const int*)d_in[2];
    const float* W1 = (const float*)d_in[3];  const float* b1 = (const float*)d_in[4];
    const float* g1 = (const float*)d_in[5];  const float* be1 = (const float*)d_in[6];
    const float* W2 = (const float*)d_in[7];  const float* b2 = (const float*)d_in[8];
    const float* g2 = (const float*)d_in[9];  const float* be2 = (const float*)d_in[10];
    const float* W3 = (const float*)d_in[11]; const float* b3 = (const float*)d_in[12];
    const float* g3 = (const float*)d_in[13]; const float* be3 = (const float*)d_in[14];
    const float* Wg = (const float*)d_in[15];
    const float* att_src = (const float*)d_in[16];
    const float* att_dst = (const float*)d_in[17];
    const float* bg = (const float*)d_in[18];
    const float* Wf = (const float*)d_in[19];
    const float* bf = (const float*)d_in[20];
    float* out = (float*)d_out;

    char* w = (char*)d_ws;
    auto alloc = [&](size_t bytes) -> char* {
        char* p = w;
        w += (bytes + 255) & ~(size_t)255;
        return p;
    };
    // --- zeroed region (one memset) ---
    int* binCur = (int*)alloc((size_t)BINS * CTR_STRIDE * 4);
    float* sums1 = (float*)alloc(64 * 4); float* ssq1 = (float*)alloc(64 * 4);
    float* sums2 = (float*)alloc(32 * 4); float* ssq2 = (float*)alloc(32 * 4);
    float* sums3 = (float*)alloc(16 * 4); float* ssq3 = (float*)alloc(16 * 4);
    size_t zeroBytes = (size_t)(w - (char*)d_ws);
    // --- rest ---
    int* binBase = (int*)alloc((size_t)BINS * 4);
    float* Psrc = (float*)alloc(128 * 4);
    float* Pdst = (float*)alloc(128 * 4);
    float* Mm = (float*)alloc(384 * 4);
    float* bgW = (float*)alloc(3 * 4);
    int* gstart = (int*)alloc((size_t)(GG + 1) * 4);
    int* rowptr = (int*)alloc((size_t)(NN + 1) * 4);
    int* colA = (int*)alloc((size_t)EE * 4);
    float* dinv = (float*)alloc((size_t)NN * 4);
    char* A = alloc((size_t)NN * 64 * 4);  // 25.6 MB scratch block A
    char* B = alloc((size_t)NN * 64 * 4);  // 25.6 MB scratch block B

    // lifetime-based aliases (byte offsets are node-row strides)
    unsigned* pairs = (unsigned*)A;  // BINS*BINREG*4 = 14.2 MB, dead after scatter_lds
    __half* xsc  = (__half*)B;                         // [NN,20] fp16   4.0 MB @ B+0
    __half* aggx = (__half*)(B + (size_t)NN * 64);     // [NN,20] fp16   4.0 MB
    __half* h1   = (__half*)A;                         // [NN,64] fp16  12.8 MB @ A+0
    __half* hs2  = (__half*)B;                         // [NN,32] fp16   6.4 MB @ B+0 (xsc dead)
    __half* h2   = (__half*)(B + (size_t)NN * 64);     // [NN,32] fp16   6.4 MB (aggx dead)
    __half* hs3  = (__half*)A;                         // [NN,16] fp16   3.2 MB (h1 dead)
    __half* h3   = (__half*)(A + (size_t)NN * 32);     // [NN,16] fp16   3.2 MB
    char*   zas  = A + (size_t)NN * 96;                // [NN,64B] z+asrc 6.4 MB
    float*  adst = (float*)(A + (size_t)NN * 160);     // [NN,8]  fp32   3.2 MB

    hipMemsetAsync(d_ws, 0, zeroBytes, stream);

    // CSR build: 128-bin pass (packed u32) + all-LDS count/scan/scatter
    bin_edges<<<256, 1024, 0, stream>>>(ei, pairs, binCur);
    bin_base<<<1, BINS, 0, stream>>>(binCur, binBase);
    scatter_lds<<<BINS, 1024, 0, stream>>>(pairs, binCur, binBase, rowptr, dinv, colA);
    gat_mats<<<1, 1024, 0, stream>>>(Wg, att_src, att_dst, Wf, bg, Psrc, Pdst, Mm, bgW);
    graph_bounds<<<(NN + 255) / 256, 256, 0, stream>>>(batch, gstart);
    pool_init<<<(GG + 255) / 256, 256, 0, stream>>>(gstart, bgW, bf, out);

    // layer 1: aggregate x first (20ch tight fp16), then GEMM 20->64 (+b1, fused BN stats)
    scale_x<<<(NN * 20 + 255) / 256, 256, 0, stream>>>(x, dinv, xsc);
    agg_half<10, 20, false><<<2048, 256, 0, stream>>>((const __half2*)xsc, rowptr, colA, dinv,
                                                      nullptr, aggx, nullptr, nullptr);
    gemm_k<20, 64, false, false, true><<<2048, 256, 0, stream>>>(
        aggx, nullptr, nullptr, nullptr, nullptr, W1, dinv, b1, h1, sums1, ssq1);

    // layer 2: 64 -> 32 (BN1 affine in-kernel; agg emits BN stats)
    gemm_k<64, 32, true, true, false><<<2048, 256, 0, stream>>>(
        h1, sums1, ssq1, g1, be1, W2, dinv, nullptr, hs2, nullptr, nullptr);
    agg_half<16, 32, true><<<2048, 256, 0, stream>>>((const __half2*)hs2, rowptr, colA, dinv,
                                                     b2, h2, sums2, ssq2);

    // layer 3: 32 -> 16
    gemm_k<32, 16, true, true, false><<<2048, 256, 0, stream>>>(
        h2, sums2, ssq2, g2, be2, W3, dinv, nullptr, hs3, nullptr, nullptr);
    agg_half<8, 16, true><<<2048, 256, 0, stream>>>((const __half2*)hs3, rowptr, colA, dinv,
                                                    b3, h3, sums3, ssq3);

    // GAT factorized: interleaved zas rows, pipelined group-per-dst agg fused with pool+classify
    gat_pre2<<<(NN + 255) / 256, 256, 0, stream>>>(h3, sums3, ssq3, g3, be3, Psrc, Pdst,
                                                   (float4*)zas, adst);
    gat_agg7<<<3200, 256, 0, stream>>>((const float4*)zas, adst, rowptr, colA, batch, Mm, out);
}

// Round 8
// 468.737 us; speedup vs baseline: 1.1358x; 1.0668x over previous
//
#include <hip/hip_runtime.h>
#include <hip/hip_fp16.h>

constexpr int NN = 100000;   // nodes
constexpr int EE = 3200000;  // edges
constexpr int GG = 5000;     // graphs
constexpr float BNEPS = 1e-5f;

// CSR build via 128 dst-bins + LDS-staged scatter
constexpr int BINS = 128;
constexpr int NPB = (NN + BINS - 1) / BINS;      // 782 nodes per bin (fits 10 bits)
constexpr int BCHUNK = 8192;                     // edges per bin_edges chunk
constexpr int NBCH = (EE + BCHUNK - 1) / BCHUNK; // 391
constexpr int BINCAP2 = 96;                      // LDS staging per bin per chunk (mean 64, +4σ)
constexpr int BINREG = 27648;                    // pairs region stride (mean 25000, +16σ)
constexpr int LCAP = 26624;                      // LDS colA buffer entries (mean+10σ)
constexpr int CTR_STRIDE = 32;                   // pad counters to separate lines

typedef int int4v __attribute__((ext_vector_type(4)));
typedef _Float16 f16x8 __attribute__((ext_vector_type(8)));

// packed pair: (dstLocal << 17) | src   — src < 131072, dstLocal < 1024

// ---------------- pass 1: bin edges by dst bin (128 bins), packed uint32 entries ----------------

__global__ __launch_bounds__(1024) void bin_edges(const int* __restrict__ ei,
                                                  unsigned* __restrict__ pairs,
                                                  int* __restrict__ binCur) {
    __shared__ int bcnt[BINS];
    __shared__ int bbase[BINS];
    __shared__ unsigned buf[BINS][BINCAP2];
    const int t = threadIdx.x;
    const int lane = t & 63, wv = t >> 6;  // 16 waves
    for (int ch = blockIdx.x; ch < NBCH; ch += gridDim.x) {
        for (int k = t; k < BINS; k += 1024) bcnt[k] = 0;
        __syncthreads();
        const int qbase = ch * (BCHUNK / 4);
#pragma unroll
        for (int rep = 0; rep < 2; ++rep) {
            const int q = qbase + rep * 1024 + t;
            if (q < EE / 4) {
                // NT here is correct: int4 loads consume the full 16B region in one
                // instruction (no sub-line reuse to destroy). NT on scalar sub-line
                // streams (R7's colA experiment) multiplies fabric traffic — reverted.
                int4v d = __builtin_nontemporal_load((const int4v*)(ei + EE) + q);
                int4v s = __builtin_nontemporal_load((const int4v*)ei + q);
                int dd[4] = {d.x, d.y, d.z, d.w};
                int ss[4] = {s.x, s.y, s.z, s.w};
#pragma unroll
                for (int k = 0; k < 4; ++k) {
                    int o = dd[k] / NPB;
                    unsigned pk = ((unsigned)(dd[k] - o * NPB) << 17) | (unsigned)ss[k];
                    int p = atomicAdd(&bcnt[o], 1);
                    if (p < BINCAP2) {
                        buf[o][p] = pk;
                    } else {  // rare overflow: direct write
                        int gp = atomicAdd(&binCur[o * CTR_STRIDE], 1);
                        pairs[(size_t)o * BINREG + gp] = pk;
                    }
                }
            }
        }
        __syncthreads();
        if (t < BINS) {
            int c = bcnt[t] < BINCAP2 ? bcnt[t] : BINCAP2;
            bbase[t] = atomicAdd(&binCur[t * CTR_STRIDE], c);
            bcnt[t] = c;
        }
        __syncthreads();
        // flush: wave wv handles bins wv, wv+16, ... (8 bins/wave, ~64 entries each)
        for (int o = wv; o < BINS; o += 16) {
            const int c = bcnt[o];
            const size_t base = (size_t)o * BINREG + bbase[o];
            for (int k = lane; k < c; k += 64) pairs[base + k] = buf[o][k];
        }
        __syncthreads();  // protect bcnt/buf reuse
    }
}

// ---------------- exclusive scan of bin totals -> global colA bases ----------------

__global__ void bin_base(const int* __restrict__ binCur, int* __restrict__ binBase) {
    __shared__ int s[BINS];
    const int t = threadIdx.x;  // 128 threads
    const int v = binCur[t * CTR_STRIDE];
    s[t] = v;
    __syncthreads();
    for (int off = 1; off < BINS; off <<= 1) {
        int add = (t >= off) ? s[t - off] : 0;
        __syncthreads();
        s[t] += add;
        __syncthreads();
    }
    binBase[t] = s[t] - v;  // exclusive
}

// ---------------- fused count + scan + scatter, one block per bin, all-LDS ----------------

__global__ __launch_bounds__(1024) void scatter_lds(const unsigned* __restrict__ pairs,
                                                    const int* __restrict__ binCur,
                                                    const int* __restrict__ binBase,
                                                    int* __restrict__ rowptr,
                                                    float* __restrict__ dinv,
                                                    int* __restrict__ colA) {
    __shared__ int scnt[NPB];     // count -> cursor
    __shared__ int sscan[1024];
    __shared__ int lbuf[LCAP];
    const int b = blockIdx.x;
    const int t = threadIdx.x;
    const int lo = b * NPB;
    const int hi = (lo + NPB < NN) ? lo + NPB : NN;
    const int nb = hi - lo;
    const int tot = binCur[b * CTR_STRIDE];
    const int base = binBase[b];
    const unsigned* p = pairs + (size_t)b * BINREG;
    for (int k = t; k < nb; k += 1024) scnt[k] = 0;
    __syncthreads();
    for (int q = t; q < tot; q += 1024) atomicAdd(&scnt[p[q] >> 17], 1);
    __syncthreads();
    const int myc = (t < nb) ? scnt[t] : 0;
    sscan[t] = myc;
    __syncthreads();
    for (int off = 1; off < 1024; off <<= 1) {
        int add = (t >= off) ? sscan[t - off] : 0;
        __syncthreads();
        sscan[t] += add;
        __syncthreads();
    }
    const int excl = sscan[t] - myc;
    if (t < nb) {
        rowptr[lo + t] = base + excl;
        dinv[lo + t] = rsqrtf((float)(myc + 1));  // +1 self-loop
        scnt[t] = excl;                           // becomes fill cursor
    }
    if (b == BINS - 1 && t == 0) rowptr[NN] = base + tot;
    __syncthreads();
    for (int q = t; q < tot; q += 1024) {
        unsigned e = p[q];
        int pos = atomicAdd(&scnt[e >> 17], 1);
        int src = (int)(e & 0x1FFFFu);
        if (pos < LCAP) lbuf[pos] = src;
        else colA[base + pos] = src;  // overflow beyond LDS cap (never expected)
    }
    __syncthreads();
    const int m = tot < LCAP ? tot : LCAP;
    for (int k = t; k < m; k += 1024) colA[base + k] = lbuf[k];
}

// ---------------- x pre-scale ----------------

__global__ void scale_x(const float* __restrict__ x, const float* __restrict__ dinv,
                        __half* __restrict__ xsc) {
    int idx = blockIdx.x * blockDim.x + threadIdx.x;
    if (idx < NN * 20) {
        int n = idx / 20;
        xsc[idx] = __float2half(x[idx] * dinv[n]);
    }
}

// ---------------- GEMM: fp16 in/out, BN-affine (from raw stats) + ReLU on input ----------------

template <int FIN, int FOUT, bool AFFINE, bool SCALED, bool STATS>
__global__ void gemm_k(const __half* __restrict__ hin,
                       const float* __restrict__ sumsIn, const float* __restrict__ ssqIn,
                       const float* __restrict__ g, const float* __restrict__ be,
                       const float* __restrict__ W, const float* __restrict__ dinv,
                       const float* __restrict__ bias,
                       __half* __restrict__ out,
                       float* __restrict__ sumsOut, float* __restrict__ ssqOut) {
    constexpr int NB = 256 / FOUT;  // nodes per group
    __shared__ float Wl[FIN * FOUT];
    __shared__ float rows[NB][FIN];
    __shared__ float aa[AFFINE ? FIN : 1], bb[AFFINE ? FIN : 1];
    const int t = threadIdx.x;
    if constexpr (AFFINE) {
        if (t < FIN) {
            float mu = sumsIn[t] / (float)NN;
            float var = ssqIn[t] / (float)NN - mu * mu;
            float a = g[t] * rsqrtf(var + BNEPS);
            aa[t] = a;
            bb[t] = be[t] - mu * a;
        }
    }
    for (int i = t; i < FIN * FOUT; i += 256) Wl[i] = W[i];
    const int c = t % FOUT, s = t / FOUT;
    const int ngrp = (NN + NB - 1) / NB;
    float sAcc = 0.f, qAcc = 0.f;
    for (int grp = blockIdx.x; grp < ngrp; grp += gridDim.x) {
        __syncthreads();
        for (int i = t; i < NB * FIN; i += 256) {
            int sn = i / FIN, k = i % FIN;
            int n2 = grp * NB + sn;
            float v = 0.f;
            if (n2 < NN) {
                v = __half2float(hin[(size_t)n2 * FIN + k]);
                if constexpr (AFFINE) {
                    v = aa[k] * v + bb[k];
                    v = v > 0.f ? v : 0.f;
                }
            }
            rows[sn][k] = v;
        }
        __syncthreads();
        int node = grp * NB + s;
        if (node < NN) {
            float acc = 0.f;
#pragma unroll
            for (int k = 0; k < FIN; ++k) acc += rows[s][k] * Wl[k * FOUT + c];
            if constexpr (SCALED) {
                out[(size_t)node * FOUT + c] = __float2half(acc * dinv[node]);
            } else {
                float val = acc + bias[c];
                out[(size_t)node * FOUT + c] = __float2half(val);
                if constexpr (STATS) { sAcc += val; qAcc += val * val; }
            }
        }
    }
    if constexpr (STATS) {
        __shared__ float ls[FOUT], lq[FOUT];
        __syncthreads();
        if (t < FOUT) { ls[t] = 0.f; lq[t] = 0.f; }
        __syncthreads();
        atomicAdd(&ls[c], sAcc);
        atomicAdd(&lq[c], qAcc);
        __syncthreads();
        if (t < FOUT) { atomicAdd(&sumsOut[t], ls[t]); atomicAdd(&ssqOut[t], lq[t]); }
    }
}

// ---------------- gather aggregation, half2-per-lane, fp16 out, optional fused BN stats ----------------
// colA loads are PLAIN cached loads: the kernel reads colA one dword at a time, so L2/L1
// line retention is what gives the stream its spatial locality. R7's NT colA loads
// multiplied colA fabric traffic ~3x (FETCH 106->134MB, dur 68->77µs). NT is only for
// full-line single-instruction streams (bin_edges int4).

template <int H2, int OUTF, bool STATS>
__global__ void agg_half(const __half2* __restrict__ src, const int* __restrict__ rowptr,
                         const int* __restrict__ colA, const float* __restrict__ dinv,
                         const float* __restrict__ bias, __half* __restrict__ out,
                         float* __restrict__ sumsOut, float* __restrict__ ssqOut) {
    constexpr int SUB = 64 / H2;
    const int lane = threadIdx.x & 63;
    const int wid = (blockIdx.x * blockDim.x + threadIdx.x) >> 6;
    const int totalWaves = (gridDim.x * blockDim.x) >> 6;
    const int f = lane % H2;
    const int sub = lane / H2;
    const int stride = totalWaves * SUB;
    float bx = 0.f, by = 0.f;
    if (bias != nullptr) {
        bx = bias[2 * f];
        by = bias[2 * f + 1];
    }
    const int i0 = (sub < SUB) ? wid * SUB + sub : NN;  // idle tail lanes skip
    float sx = 0.f, qx = 0.f, sy = 0.f, qy = 0.f;
    for (int i = i0; i < NN; i += stride) {
        const int r0 = rowptr[i], r1 = rowptr[i + 1];
        float2 acc = __half22float2(src[(size_t)i * H2 + f]);
        float2 acc2 = {0.f, 0.f};
        int e = r0;
        for (; e + 3 < r1; e += 4) {
            int j0 = colA[e], j1 = colA[e + 1], j2 = colA[e + 2], j3 = colA[e + 3];
            float2 v0 = __half22float2(src[(size_t)j0 * H2 + f]);
            float2 v1 = __half22float2(src[(size_t)j1 * H2 + f]);
            float2 v2 = __half22float2(src[(size_t)j2 * H2 + f]);
            float2 v3 = __half22float2(src[(size_t)j3 * H2 + f]);
            acc.x += v0.x + v1.x;
            acc.y += v0.y + v1.y;
            acc2.x += v2.x + v3.x;
            acc2.y += v2.y + v3.y;
        }
        for (; e < r1; ++e) {
            float2 v = __half22float2(src[(size_t)colA[e] * H2 + f]);
            acc.x += v.x; acc.y += v.y;
        }
        acc.x += acc2.x; acc.y += acc2.y;
        const float d = dinv[i];
        float vx = d * acc.x + bx;
        float vy = d * acc.y + by;
        *(__half2*)(out + (size_t)i * OUTF + 2 * f) = __floats2half2_rn(vx, vy);
        if constexpr (STATS) { sx += vx; qx += vx * vx; sy += vy; qy += vy * vy; }
    }
    if constexpr (STATS) {
        __shared__ float ls[OUTF], lq[OUTF];
        const int t = threadIdx.x;
        if (t < OUTF) { ls[t] = 0.f; lq[t] = 0.f; }
        __syncthreads();
        atomicAdd(&ls[2 * f], sx);
        atomicAdd(&lq[2 * f], qx);
        atomicAdd(&ls[2 * f + 1], sy);
        atomicAdd(&lq[2 * f + 1], qy);
        __syncthreads();
        if (t < OUTF) { atomicAdd(&sumsOut[t], ls[t]); atomicAdd(&ssqOut[t], lq[t]); }
    }
}

// ---------------- GAT factorized precompute ----------------

__global__ void gat_mats(const float* __restrict__ Wg, const float* __restrict__ att_src,
                         const float* __restrict__ att_dst, const float* __restrict__ Wf,
                         const float* __restrict__ bg, float* __restrict__ Psrc,
                         float* __restrict__ Pdst, float* __restrict__ M,
                         float* __restrict__ bgW) {
    int t = threadIdx.x;  // 1024 threads, one block
    if (t < 128) {
        int k = t >> 3, h = t & 7;
        float s = 0.f, d = 0.f;
        for (int c = 0; c < 16; ++c) {
            float wv = Wg[k * 128 + h * 16 + c];
            s += wv * att_src[h * 16 + c];
            d += wv * att_dst[h * 16 + c];
        }
        Psrc[k * 8 + h] = s;
        Pdst[k * 8 + h] = d;
    } else if (t < 512) {
        int m = t - 128;
        if (m < 384) {
            int hk = m / 3, j = m - hk * 3;
            int H = hk >> 4, k = hk & 15;
            float s = 0.f;
            for (int c = 0; c < 16; ++c) s += Wg[k * 128 + H * 16 + c] * Wf[c * 3 + j];
            M[hk * 3 + j] = 0.125f * s;
        }
    } else if (t < 515) {
        int j = t - 512;
        float s = 0.f;
        for (int c = 0; c < 16; ++c) s += bg[c] * Wf[c * 3 + j];
        bgW[j] = s;
    }
}

// ---------------- gat_pre2: interleaved zas row [z fp16 32B | asrc fp32 32B] + adst ----------------

__global__ void gat_pre2(const __half* __restrict__ h3,
                         const float* __restrict__ sums3, const float* __restrict__ ssq3,
                         const float* __restrict__ g3, const float* __restrict__ be3,
                         const float* __restrict__ Psrc, const float* __restrict__ Pdst,
                         float4* __restrict__ zas, float* __restrict__ adst) {
    __shared__ float Ps[128], Pd[128], aa[16], bb[16];
    int t = threadIdx.x;
    if (t < 128) { Ps[t] = Psrc[t]; Pd[t] = Pdst[t]; }
    if (t < 16) {
        float mu = sums3[t] / (float)NN;
        float var = ssq3[t] / (float)NN - mu * mu;
        float a = g3[t] * rsqrtf(var + BNEPS);
        aa[t] = a;
        bb[t] = be3[t] - mu * a;
    }
    __syncthreads();
    int n = blockIdx.x * blockDim.x + t;
    if (n >= NN) return;
    const f16x8* hp = (const f16x8*)(h3 + (size_t)n * 16);
    f16x8 v0 = hp[0], v1 = hp[1];
    float zv[16];
#pragma unroll
    for (int k = 0; k < 8; ++k) {
        float a0 = aa[k] * (float)v0[k] + bb[k];
        float a1 = aa[8 + k] * (float)v1[k] + bb[8 + k];
        zv[k] = a0 > 0.f ? a0 : 0.f;
        zv[8 + k] = a1 > 0.f ? a1 : 0.f;
    }
    f16x8 zh0, zh1;
#pragma unroll
    for (int k = 0; k < 8; ++k) {
        zh0[k] = (_Float16)zv[k];
        zh1[k] = (_Float16)zv[8 + k];
    }
    float as[8], ad[8];
#pragma unroll
    for (int h = 0; h < 8; ++h) { as[h] = 0.f; ad[h] = 0.f; }
#pragma unroll
    for (int k = 0; k < 16; ++k) {
        float zk = zv[k];
#pragma unroll
        for (int h = 0; h < 8; ++h) {
            as[h] += zk * Ps[k * 8 + h];
            ad[h] += zk * Pd[k * 8 + h];
        }
    }
    f16x8* zrow16 = (f16x8*)(zas + (size_t)n * 4);  // 64B row: [0..31]=z fp16, [32..63]=asrc fp32
    zrow16[0] = zh0;
    zrow16[1] = zh1;
    float4* zrow = zas + (size_t)n * 4;
    zrow[2] = make_float4(as[0], as[1], as[2], as[3]);
    zrow[3] = make_float4(as[4], as[5], as[6], as[7]);
    float4* d4 = (float4*)(adst + (size_t)n * 8);
    d4[0] = make_float4(ad[0], ad[1], ad[2], ad[3]);
    d4[1] = make_float4(ad[4], ad[5], ad[6], ad[7]);
}

// ---------------- gat_agg7: group-per-dst, 2-wide pipelined gathers, fused M-projection ----------------
// Verified @67.7µs, VGPR 60, WRITE 3.7MB. Head-per-lane variants (agg8/9) hit a structural
// SROA failure (64-float state across irregular loop -> scratch, 66-72MB writes) twice.

__device__ __forceinline__ float leaky02(float x) { return x > 0.f ? x : 0.2f * x; }

__global__ void gat_agg7(const float4* __restrict__ zas, const float* __restrict__ adst,
                         const int* __restrict__ rowptr, const int* __restrict__ colA,
                         const int* __restrict__ batch, const float* __restrict__ Mg,
                         float* __restrict__ out) {
    __shared__ float Ml[384];
    for (int k = threadIdx.x; k < 384; k += 256) Ml[k] = Mg[k];
    __syncthreads();
    const int lane = threadIdx.x & 63;
    const int ls = lane & 7;        // lane within group: also the head this lane exp's
    const int q = ls & 3;           // channel quad
    const int hh = ls >> 2;         // head half
    const int grp = lane >> 3;      // 8 dst-groups per wave
    const int gb = lane & 56;       // group base lane for shuffles
    const int wid = (blockIdx.x * blockDim.x + threadIdx.x) >> 6;
    const int totalWaves = (gridDim.x * blockDim.x) >> 6;
    const int stride = totalWaves * 8;
    const char* zb = (const char*)zas;
    for (int i = wid * 8 + grp; i < NN; i += stride) {
        const int r0 = rowptr[i], r1 = rowptr[i + 1];
        const float adv = __builtin_nontemporal_load(adst + (size_t)i * 8 + ls);
        float acc[4][4];
        float wsum[4];
#pragma unroll
        for (int h = 0; h < 4; ++h) {
            wsum[h] = 0.f;
#pragma unroll
            for (int k = 0; k < 4; ++k) acc[h][k] = 0.f;
        }
        auto compute = [&](float av, float2 zr, bool val) {
            const __half2* zp = (const __half2*)&zr;
            const float2 f0 = __half22float2(zp[0]), f1 = __half22float2(zp[1]);
            const float zf[4] = {f0.x, f0.y, f1.x, f1.y};
            const float w = val ? __expf(leaky02(av + adv)) : 0.f;
            float wq[4];
#pragma unroll
            for (int h = 0; h < 4; ++h) wq[h] = __shfl(w, gb + hh * 4 + h);
#pragma unroll
            for (int h = 0; h < 4; ++h) {
                wsum[h] += wq[h];
#pragma unroll
                for (int k = 0; k < 4; ++k) acc[h][k] += wq[h] * zf[k];
            }
        };
        // prologue: pair 0 = (self, first edge)
        int e = r0;
        int jA = i, jB = i;
        bool vB = false;
        if (e < r1) { jB = colA[e]; ++e; vB = true; }
        const char* rowA = zb + (size_t)jA * 64;
        const char* rowB = zb + (size_t)jB * 64;
        float avA = *(const float*)(rowA + 32 + ls * 4);
        float2 zA = *(const float2*)(rowA + q * 8);
        float avB = *(const float*)(rowB + 32 + ls * 4);
        float2 zB = *(const float2*)(rowB + q * 8);
        while (true) {
            // prefetch next pair (indices then rows) BEFORE computing current pair
            int jA2 = i, jB2 = i;
            bool vA2 = false, vB2 = false;
            if (e < r1) { jA2 = colA[e]; ++e; vA2 = true; }
            if (e < r1) { jB2 = colA[e]; ++e; vB2 = true; }
            const char* rA2 = zb + (size_t)jA2 * 64;
            const char* rB2 = zb + (size_t)jB2 * 64;
            float avA2 = *(const float*)(rA2 + 32 + ls * 4);
            float2 zA2 = *(const float2*)(rA2 + q * 8);
            float avB2 = *(const float*)(rB2 + 32 + ls * 4);
            float2 zB2 = *(const float2*)(rB2 + q * 8);
            compute(avA, zA, true);   // A slot of in-flight pair is always valid
            compute(avB, zB, vB);
            if (!vA2) break;
            avA = avA2; zA = zA2; avB = avB2; zB = zB2; vB = vB2;
        }
        // epilogue: normalize, project through M, group-reduce, atomic into out[graph]
        float o0 = 0.f, o1 = 0.f, o2 = 0.f;
#pragma unroll
        for (int h = 0; h < 4; ++h) {
            const float inv = 1.f / wsum[h];
            const int hk0 = (hh * 4 + h) * 16 + q * 4;
#pragma unroll
            for (int k = 0; k < 4; ++k) {
                const float v = acc[h][k] * inv;
                const float* m = &Ml[(hk0 + k) * 3];
                o0 += v * m[0];
                o1 += v * m[1];
                o2 += v * m[2];
            }
        }
#pragma unroll
        for (int off = 1; off < 8; off <<= 1) {
            o0 += __shfl_xor(o0, off);
            o1 += __shfl_xor(o1, off);
            o2 += __shfl_xor(o2, off);
        }
        const int g = batch[i];
        if (ls < 3) {
            const float ov = (ls == 0) ? o0 : (ls == 1) ? o1 : o2;
            atomicAdd(&out[g * 3 + ls], ov);
        }
    }
}

// ---------------- graph bounds from sorted batch ----------------

__global__ void graph_bounds(const int* __restrict__ batch, int* __restrict__ gstart) {
    int n = blockIdx.x * blockDim.x + threadIdx.x;
    if (n < NN) {
        int bn = batch[n];
        int bp = (n == 0) ? -1 : batch[n - 1];
        for (int g = bp + 1; g <= bn; ++g) gstart[g] = n;
        if (n == NN - 1)
            for (int g = bn + 1; g <= GG; ++g) gstart[g] = NN;
    }
}

// ---------------- pool_init: out[g] = bf + cnt*bgW (gat_agg7 atomically accumulates rest) ----------------

__global__ void pool_init(const int* __restrict__ gstart, const float* __restrict__ bgW,
                          const float* __restrict__ bf, float* __restrict__ out) {
    int g = blockIdx.x * blockDim.x + threadIdx.x;
    if (g < GG) {
        float cnt = (float)(gstart[g + 1] - gstart[g]);
#pragma unroll
        for (int j = 0; j < 3; ++j) out[g * 3 + j] = cnt * bgW[j] + bf[j];
    }
}

// ---------------- launcher ----------------

extern "C" void kernel_launch(void* const* d_in, const int* in_sizes, int n_in,
                              void* d_out, int out_size, void* d_ws, size_t ws_size,
                              hipStream_t stream) {
    const float* x = (const float*)d_in[0];
    const int* ei = (const int*)d_in[1];
    const int* batch = (const int*)d_in[2];
    const float* W1 = (const float*)d_in[3];  const float* b1 = (const float*)d_in[4];
    const float* g1 = (const float*)d_in[5];  const float* be1 = (const float*)d_in[6];
    const float* W2 = (const float*)d_in[7];  const float* b2 = (const float*)d_in[8];
    const float* g2 = (const float*)d_in[9];  const float* be2 = (const float*)d_in[10];
    const float* W3 = (const float*)d_in[11]; const float* b3 = (const float*)d_in[12];
    const float* g3 = (const float*)d_in[13]; const float* be3 = (const float*)d_in[14];
    const float* Wg = (const float*)d_in[15];
    const float* att_src = (const float*)d_in[16];
    const float* att_dst = (const float*)d_in[17];
    const float* bg = (const float*)d_in[18];
    const float* Wf = (const float*)d_in[19];
    const float* bf = (const float*)d_in[20];
    float* out = (float*)d_out;

    char* w = (char*)d_ws;
    auto alloc = [&](size_t bytes) -> char* {
        char* p = w;
        w += (bytes + 255) & ~(size_t)255;
        return p;
    };
    // --- zeroed region (one memset) ---
    int* binCur = (int*)alloc((size_t)BINS * CTR_STRIDE * 4);
    float* sums1 = (float*)alloc(64 * 4); float* ssq1 = (float*)alloc(64 * 4);
    float* sums2 = (float*)alloc(32 * 4); float* ssq2 = (float*)alloc(32 * 4);
    float* sums3 = (float*)alloc(16 * 4); float* ssq3 = (float*)alloc(16 * 4);
    size_t zeroBytes = (size_t)(w - (char*)d_ws);
    // --- rest ---
    int* binBase = (int*)alloc((size_t)BINS * 4);
    float* Psrc = (float*)alloc(128 * 4);
    float* Pdst = (float*)alloc(128 * 4);
    float* Mm = (float*)alloc(384 * 4);
    float* bgW = (float*)alloc(3 * 4);
    int* gstart = (int*)alloc((size_t)(GG + 1) * 4);
    int* rowptr = (int*)alloc((size_t)(NN + 1) * 4);
    int* colA = (int*)alloc((size_t)EE * 4);
    float* dinv = (float*)alloc((size_t)NN * 4);
    char* A = alloc((size_t)NN * 64 * 4);  // 25.6 MB scratch block A
    char* B = alloc((size_t)NN * 64 * 4);  // 25.6 MB scratch block B

    // lifetime-based aliases (byte offsets are node-row strides)
    unsigned* pairs = (unsigned*)A;  // BINS*BINREG*4 = 14.2 MB, dead after scatter_lds
    __half* xsc  = (__half*)B;                         // [NN,20] fp16   4.0 MB @ B+0
    __half* aggx = (__half*)(B + (size_t)NN * 64);     // [NN,20] fp16   4.0 MB
    __half* h1   = (__half*)A;                         // [NN,64] fp16  12.8 MB @ A+0
    __half* hs2  = (__half*)B;                         // [NN,32] fp16   6.4 MB @ B+0 (xsc dead)
    __half* h2   = (__half*)(B + (size_t)NN * 64);     // [NN,32] fp16   6.4 MB (aggx dead)
    __half* hs3  = (__half*)A;                         // [NN,16] fp16   3.2 MB (h1 dead)
    __half* h3   = (__half*)(A + (size_t)NN * 32);     // [NN,16] fp16   3.2 MB
    char*   zas  = A + (size_t)NN * 96;                // [NN,64B] z+asrc 6.4 MB
    float*  adst = (float*)(A + (size_t)NN * 160);     // [NN,8]  fp32   3.2 MB

    hipMemsetAsync(d_ws, 0, zeroBytes, stream);

    // CSR build: 128-bin pass (packed u32) + all-LDS count/scan/scatter
    bin_edges<<<256, 1024, 0, stream>>>(ei, pairs, binCur);
    bin_base<<<1, BINS, 0, stream>>>(binCur, binBase);
    scatter_lds<<<BINS, 1024, 0, stream>>>(pairs, binCur, binBase, rowptr, dinv, colA);
    gat_mats<<<1, 1024, 0, stream>>>(Wg, att_src, att_dst, Wf, bg, Psrc, Pdst, Mm, bgW);
    graph_bounds<<<(NN + 255) / 256, 256, 0, stream>>>(batch, gstart);
    pool_init<<<(GG + 255) / 256, 256, 0, stream>>>(gstart, bgW, bf, out);

    // layer 1: aggregate x first (20ch tight fp16), then GEMM 20->64 (+b1, fused BN stats)
    scale_x<<<(NN * 20 + 255) / 256, 256, 0, stream>>>(x, dinv, xsc);
    agg_half<10, 20, false><<<2048, 256, 0, stream>>>((const __half2*)xsc, rowptr, colA, dinv,
                                                      nullptr, aggx, nullptr, nullptr);
    gemm_k<20, 64, false, false, true><<<2048, 256, 0, stream>>>(
        aggx, nullptr, nullptr, nullptr, nullptr, W1, dinv, b1, h1, sums1, ssq1);

    // layer 2: 64 -> 32 (BN1 affine in-kernel; agg emits BN stats)
    gemm_k<64, 32, true, true, false><<<2048, 256, 0, stream>>>(
        h1, sums1, ssq1, g1, be1, W2, dinv, nullptr, hs2, nullptr, nullptr);
    agg_half<16, 32, true><<<2048, 256, 0, stream>>>((const __half2*)hs2, rowptr, colA, dinv,
                                                     b2, h2, sums2, ssq2);

    // layer 3: 32 -> 16
    gemm_k<32, 16, true, true, false><<<2048, 256, 0, stream>>>(
        h2, sums2, ssq2, g2, be2, W3, dinv, nullptr, hs3, nullptr, nullptr);
    agg_half<8, 16, true><<<2048, 256, 0, stream>>>((const __half2*)hs3, rowptr, colA, dinv,
                                                    b3, h3, sums3, ssq3);

    // GAT factorized: interleaved zas rows, pipelined group-per-dst agg fused with pool+classify
    gat_pre2<<<(NN + 255) / 256, 256, 0, stream>>>(h3, sums3, ssq3, g3, be3, Psrc, Pdst,
                                                   (float4*)zas, adst);
    gat_agg7<<<3200, 256, 0, stream>>>((const float4*)zas, adst, rowptr, colA, batch, Mm, out);
}